// Round 11
// baseline (2037.535 us; speedup 1.0000x reference)
//
#include <hip/hip_runtime.h>

// Scatter-mean graph propagation, 8 rounds (4 fwd + 4 rev).
//
// ROUND-11: r10 showed e_pass is gather-lookup-bound (190us invariant to
// unroll/BW/bucket-size; 64 distinct lines per wave-gather, ~0% L1 hit).
// Fix: order edges by src WITHIN each dst-bucket via a 2-pass radix:
//   pass 1: partition by src>>12 (245 buckets), e1=(dst<<12)|(src&4095)
//   pass 2: partition e1 by dst>>12 (245 buckets) with the same staged
//           scatter (order-preserving at batch granularity); full src
//           recovered as (sb<<12)|(e1&4095) where sb = pass-1 bucket,
//           found by binary search over LDS-cached pass-1 bases.
//           final entry = (src<<12)|(dst&4095).
// e_pass then uses the SIMPLE lane-contiguous loop: a wave's 64 consecutive
// (src-sorted) edges span ~31 cache lines (merge) and stay in a 16KB window
// (L1-resident) -> L2 requests drop ~4x.
//
// MID PATH (ws too small for e1): single-pass dst partition + same e_pass
// (r10-equivalent, 1742us proven).
// FALLBACK: global-atomic version.

typedef unsigned uint32x4 __attribute__((ext_vector_type(4)));

#define TPB_E 1024
#define NPART 512
#define TPB_P 512
#define BATCH 8192
#define CAP 64
#define NBMAX 256      // max buckets per radix digit (N <= 2^20)
#define KSH 12         // bucket shift (4096 values per bucket)
#define KMASK 4095u

// ---------------- generic partition machinery ----------------

// histogram of keys[i]>>shift per partition block
__global__ __launch_bounds__(TPB_P)
void p1_count(const unsigned* __restrict__ keys, unsigned* __restrict__ blkcnt,
              int E, int chunk, int NB, int shift) {
    __shared__ unsigned h[NBMAX];
    for (int i = threadIdx.x; i < NB; i += TPB_P) h[i] = 0u;
    __syncthreads();
    int beg = blockIdx.x * chunk;
    int end = min(beg + chunk, E);
    int len = end - beg; if (len < 0) len = 0;
    const uint32x4* k4 = (const uint32x4*)(keys + beg);   // beg multiple of 16
    int n4 = len >> 2;
    for (int i = threadIdx.x; i < n4; i += TPB_P) {
        uint32x4 k = __builtin_nontemporal_load(&k4[i]);
        atomicAdd(&h[k.x >> shift], 1u);
        atomicAdd(&h[k.y >> shift], 1u);
        atomicAdd(&h[k.z >> shift], 1u);
        atomicAdd(&h[k.w >> shift], 1u);
    }
    __syncthreads();
    unsigned* o = blkcnt + (size_t)blockIdx.x * NB;
    for (int i = threadIdx.x; i < NB; i += TPB_P) o[i] = h[i];
}

__global__ __launch_bounds__(TPB_P)
void s1_totals(const unsigned* __restrict__ blkcnt, unsigned* __restrict__ totals,
               int NB, int nblk) {
    __shared__ unsigned red[TPB_P];
    int b = blockIdx.x;
    unsigned s = 0;
    for (int k = threadIdx.x; k < nblk; k += TPB_P) s += blkcnt[(size_t)k * NB + b];
    red[threadIdx.x] = s;
    __syncthreads();
    for (int off = TPB_P / 2; off > 0; off >>= 1) {
        if (threadIdx.x < off) red[threadIdx.x] += red[threadIdx.x + off];
        __syncthreads();
    }
    if (threadIdx.x == 0) totals[b] = red[0];
}

__global__ __launch_bounds__(TPB_P)
void s2_scan(const unsigned* __restrict__ totals, unsigned* __restrict__ base, int NB) {
    __shared__ unsigned t[TPB_P];
    int tid = threadIdx.x;
    unsigned v = (tid < NB) ? totals[tid] : 0u;
    t[tid] = v;
    __syncthreads();
    for (int off = 1; off < TPB_P; off <<= 1) {
        unsigned w = (tid >= off) ? t[tid - off] : 0u;
        __syncthreads();
        t[tid] += w;
        __syncthreads();
    }
    if (tid < NB) base[tid] = t[tid] - v;
    if (tid == NB - 1) base[NB] = t[tid];
}

__global__ __launch_bounds__(TPB_P)
void s3_start(const unsigned* __restrict__ blkcnt, const unsigned* __restrict__ base,
              unsigned* __restrict__ start, int NB, int nblk) {
    __shared__ unsigned t[TPB_P];
    int b = blockIdx.x;
    int tid = threadIdx.x;
    unsigned v = (tid < nblk) ? blkcnt[(size_t)tid * NB + b] : 0u;
    t[tid] = v;
    __syncthreads();
    for (int off = 1; off < TPB_P; off <<= 1) {
        unsigned w = (tid >= off) ? t[tid - off] : 0u;
        __syncthreads();
        t[tid] += w;
        __syncthreads();
    }
    if (tid < nblk) start[(size_t)tid * NB + b] = base[b] + t[tid] - v;
}

// staged scatter of a (keys, other) pair: bucket = keys>>KSH,
// val = (other<<KSH)|(keys&KMASK). LDS-staged, wave-coalesced flush.
__global__ __launch_bounds__(TPB_P)
void p2_pair(const unsigned* __restrict__ keys, const unsigned* __restrict__ other,
             const unsigned* __restrict__ start, unsigned* __restrict__ outbuf,
             int E, int chunk, int NB) {
    __shared__ unsigned stg[NBMAX * CAP];   // 64 KB
    __shared__ unsigned h[NBMAX];
    __shared__ unsigned gcur[NBMAX];
    int tid = threadIdx.x;
    int bid = blockIdx.x;
    for (int i = tid; i < NB; i += TPB_P) gcur[i] = start[(size_t)bid * NB + i];
    int beg = bid * chunk;
    int end = min(beg + chunk, E);
    int wid = tid >> 6, lane = tid & 63;
    for (int bb = beg; bb < end; bb += BATCH) {
        int bend = min(bb + BATCH, end);
        int n4 = (bend - bb) >> 2;
        for (int i = tid; i < NB; i += TPB_P) h[i] = 0u;
        __syncthreads();
        const uint32x4* k4 = (const uint32x4*)(keys + bb);
        const uint32x4* o4 = (const uint32x4*)(other + bb);
        for (int i = tid; i < n4; i += TPB_P) {
            uint32x4 k = __builtin_nontemporal_load(&k4[i]);
            uint32x4 o = __builtin_nontemporal_load(&o4[i]);
            unsigned kv[4] = {k.x, k.y, k.z, k.w};
            unsigned ov[4] = {o.x, o.y, o.z, o.w};
            #pragma unroll
            for (int q = 0; q < 4; ++q) {
                unsigned b = kv[q] >> KSH;
                unsigned val = (ov[q] << KSH) | (kv[q] & KMASK);
                unsigned pos = atomicAdd(&h[b], 1u);
                if (pos < CAP) stg[(b << 6) + ((pos + b) & 63u)] = val;
                else outbuf[gcur[b] + pos] = val;   // rare overflow, exact position
            }
        }
        __syncthreads();
        for (int b = wid; b < NB; b += TPB_P / 64) {
            unsigned cnt = h[b];
            unsigned n = cnt < CAP ? cnt : CAP;
            unsigned g0 = gcur[b];
            for (unsigned i = lane; i < n; i += 64)
                outbuf[g0 + i] = stg[(b << 6) + ((i + b) & 63u)];
            if (lane == 0) gcur[b] = g0 + cnt;
        }
        __syncthreads();
    }
}

// pass-2: scatter e1 by dst>>12; recover full src via binary search on base1.
__global__ __launch_bounds__(TPB_P)
void p2b_scatter(const unsigned* __restrict__ e1, const unsigned* __restrict__ base1,
                 const unsigned* __restrict__ start, unsigned* __restrict__ packed,
                 int E, int chunk, int NB, int NB1) {
    __shared__ unsigned stg[NBMAX * CAP];   // 64 KB
    __shared__ unsigned h[NBMAX];
    __shared__ unsigned gcur[NBMAX];
    __shared__ unsigned b1[NBMAX + 1];
    int tid = threadIdx.x;
    int bid = blockIdx.x;
    for (int i = tid; i < NB; i += TPB_P) gcur[i] = start[(size_t)bid * NB + i];
    for (int i = tid; i <= NB1; i += TPB_P) b1[i] = base1[i];
    int beg = bid * chunk;
    int end = min(beg + chunk, E);
    int wid = tid >> 6, lane = tid & 63;
    for (int bb = beg; bb < end; bb += BATCH) {
        int bend = min(bb + BATCH, end);
        int n4 = (bend - bb) >> 2;
        for (int i = tid; i < NB; i += TPB_P) h[i] = 0u;
        __syncthreads();
        const uint32x4* q4 = (const uint32x4*)(e1 + bb);
        for (int i = tid; i < n4; i += TPB_P) {
            uint32x4 q = __builtin_nontemporal_load(&q4[i]);
            int e0 = bb + (i << 2);
            int lo = 0, hi = NB1;               // b1[lo] <= e0 < b1[hi]
            while (hi - lo > 1) {
                int mid = (lo + hi) >> 1;
                if ((unsigned)e0 >= b1[mid]) lo = mid; else hi = mid;
            }
            unsigned sb = (unsigned)lo;
            unsigned qa[4] = {q.x, q.y, q.z, q.w};
            #pragma unroll
            for (int k = 0; k < 4; ++k) {
                while ((unsigned)(e0 + k) >= b1[sb + 1]) sb++;
                unsigned qv = qa[k];
                unsigned b = qv >> 24;                          // dst>>12
                unsigned srcf = (sb << KSH) | (qv & KMASK);     // full src
                unsigned val = (srcf << KSH) | ((qv >> KSH) & KMASK);
                unsigned pos = atomicAdd(&h[b], 1u);
                if (pos < CAP) stg[(b << 6) + ((pos + b) & 63u)] = val;
                else packed[gcur[b] + pos] = val;
            }
        }
        __syncthreads();
        for (int b = wid; b < NB; b += TPB_P / 64) {
            unsigned cnt = h[b];
            unsigned n = cnt < CAP ? cnt : CAP;
            unsigned g0 = gcur[b];
            for (unsigned i = lane; i < n; i += 64)
                packed[g0 + i] = stg[(b << 6) + ((i + b) & 63u)];
            if (lane == 0) gcur[b] = g0 + cnt;
        }
        __syncthreads();
    }
}

// ---------------- e_pass: lane-contiguous gather (benefits from src order) ----------------

template <bool FIRST>
__global__ __launch_bounds__(TPB_E)
void e_pass(const float* __restrict__ x, const unsigned* __restrict__ packed,
            const unsigned* __restrict__ boff, float* __restrict__ rcnt,
            float* __restrict__ outslice, int N) {
    __shared__ float acc[1 << KSH];             // 16 KB
    __shared__ unsigned c[FIRST ? (1 << KSH) : 1];
    int tid = threadIdx.x;
    for (int i = tid; i < (1 << KSH); i += TPB_E) {
        acc[i] = 0.0f;
        if (FIRST) c[i] = 0u;
    }
    __syncthreads();
    int b = blockIdx.x;
    int beg = (int)boff[b], end = (int)boff[b + 1];
    // lane-contiguous: a wave reads 64 consecutive (src-sorted) edges
    for (int e = beg + tid; e < end; e += TPB_E) {
        unsigned p = __builtin_nontemporal_load(&packed[e]);
        atomicAdd(&acc[p & KMASK], x[p >> KSH]);
        if (FIRST) atomicAdd(&c[p & KMASK], 1u);
    }
    __syncthreads();
    int nbase = b << KSH;
    for (int i = tid; i < (1 << KSH); i += TPB_E) {
        int node = nbase + i;
        if (node < N) {
            float rc;
            if (FIRST) {
                unsigned cv = c[i];
                rc = 1.0f / (float)(cv > 0u ? cv : 1u);
                rcnt[node] = rc;
            } else {
                rc = rcnt[node];
            }
            outslice[node] = acc[i] * rc;
        }
    }
}

// ---------------- fallback (global atomics) ----------------

#define TPB 256
#define MAX_BLOCKS 2048

__global__ void round_first(const float* __restrict__ x, const int* __restrict__ src,
                            const int* __restrict__ dst, float* __restrict__ agg,
                            float* __restrict__ cnt, int nE) {
    int i = blockIdx.x * blockDim.x + threadIdx.x;
    int stride = gridDim.x * blockDim.x;
    for (; i < nE; i += stride) {
        atomicAdd(&agg[dst[i]], x[src[i]]);
        atomicAdd(&cnt[dst[i]], 1.0f);
    }
}

__global__ void round_next(const float* __restrict__ x, const int* __restrict__ src,
                           const int* __restrict__ dst, float* __restrict__ agg, int nE) {
    int i = blockIdx.x * blockDim.x + threadIdx.x;
    int stride = gridDim.x * blockDim.x;
    for (; i < nE; i += stride) atomicAdd(&agg[dst[i]], x[src[i]]);
}

__global__ void normalize_k(float* __restrict__ out, const float* __restrict__ cnt, int n) {
    int i = blockIdx.x * blockDim.x + threadIdx.x;
    int stride = gridDim.x * blockDim.x;
    for (; i < n; i += stride) out[i] /= fmaxf(cnt[i], 1.0f);
}

// ---------------- launch ----------------

extern "C" void kernel_launch(void* const* d_in, const int* in_sizes, int n_in,
                              void* d_out, int out_size, void* d_ws, size_t ws_size,
                              hipStream_t stream) {
    const float* topic = (const float*)d_in[0];
    const int* ei  = (const int*)d_in[1];
    const int* rei = (const int*)d_in[2];
    const int N = in_sizes[0];
    const int E = in_sizes[1] / 2;

    float* out = (float*)d_out;   // 8 slices of N floats

    const int NB = (N + (int)KMASK) >> KSH;   // buckets for both radix digits
    const int chunk = ((E + NPART * 16 - 1) / (NPART * 16)) * 16;

    size_t off = 0;
    auto alloc = [&](size_t bytes) { size_t o = off; off += (bytes + 255) & ~(size_t)255; return o; };
    size_t o_packed = alloc((size_t)E * 4);
    size_t o_cnt    = alloc((size_t)N * 4);
    size_t o_blkcnt = alloc((size_t)NPART * NB * 4);
    size_t o_start  = alloc((size_t)NPART * NB * 4);
    size_t o_totals = alloc((size_t)NBMAX * 4);
    size_t o_base1  = alloc((size_t)(NBMAX + 1) * 4);
    size_t o_base2  = alloc((size_t)(NBMAX + 1) * 4);
    size_t need_mid = off;
    size_t o_e1     = alloc((size_t)E * 4);
    size_t need_full = off;

    bool shapes_ok = (NB >= 2) && (NB <= NBMAX) && (N <= (1 << 20)) &&
                     (E % 16 == 0) && (E > 0);
    bool full = shapes_ok && (need_full <= ws_size);
    bool mid  = shapes_ok && (need_mid <= ws_size);

    if (full || mid) {
        char* ws = (char*)d_ws;
        unsigned* packed = (unsigned*)(ws + o_packed);
        float*    rcnt   = (float*)   (ws + o_cnt);
        unsigned* blkcnt = (unsigned*)(ws + o_blkcnt);
        unsigned* start  = (unsigned*)(ws + o_start);
        unsigned* totals = (unsigned*)(ws + o_totals);
        unsigned* base1  = (unsigned*)(ws + o_base1);
        unsigned* base2  = (unsigned*)(ws + o_base2);
        unsigned* e1     = full ? (unsigned*)(ws + o_e1) : nullptr;

        for (int dir = 0; dir < 2; ++dir) {
            const unsigned* src = (const unsigned*)((dir == 0) ? ei : rei);
            const unsigned* dst = src + E;
            float* oslab = out + (size_t)dir * 4 * N;

            if (full) {
                // pass 1: partition by src>>12, e1=(dst<<12)|(src&4095)
                p1_count<<<NPART, TPB_P, 0, stream>>>(src, blkcnt, E, chunk, NB, KSH);
                s1_totals<<<NB, TPB_P, 0, stream>>>(blkcnt, totals, NB, NPART);
                s2_scan<<<1, TPB_P, 0, stream>>>(totals, base1, NB);
                s3_start<<<NB, TPB_P, 0, stream>>>(blkcnt, base1, start, NB, NPART);
                p2_pair<<<NPART, TPB_P, 0, stream>>>(src, dst, start, e1, E, chunk, NB);
                // pass 2: partition e1 by dst>>12 (e1>>24), src-order preserved
                p1_count<<<NPART, TPB_P, 0, stream>>>(e1, blkcnt, E, chunk, NB, 24);
                s1_totals<<<NB, TPB_P, 0, stream>>>(blkcnt, totals, NB, NPART);
                s2_scan<<<1, TPB_P, 0, stream>>>(totals, base2, NB);
                s3_start<<<NB, TPB_P, 0, stream>>>(blkcnt, base2, start, NB, NPART);
                p2b_scatter<<<NPART, TPB_P, 0, stream>>>(e1, base1, start, packed,
                                                         E, chunk, NB, NB);
            } else {
                // single-pass dst partition (r10-equivalent)
                p1_count<<<NPART, TPB_P, 0, stream>>>(dst, blkcnt, E, chunk, NB, KSH);
                s1_totals<<<NB, TPB_P, 0, stream>>>(blkcnt, totals, NB, NPART);
                s2_scan<<<1, TPB_P, 0, stream>>>(totals, base2, NB);
                s3_start<<<NB, TPB_P, 0, stream>>>(blkcnt, base2, start, NB, NPART);
                p2_pair<<<NPART, TPB_P, 0, stream>>>(dst, src, start, packed, E, chunk, NB);
            }

            e_pass<true><<<NB, TPB_E, 0, stream>>>(topic, packed, base2, rcnt, oslab, N);
            for (int r = 1; r < 4; ++r) {
                e_pass<false><<<NB, TPB_E, 0, stream>>>(oslab + (size_t)(r - 1) * N, packed,
                                                        base2, rcnt, oslab + (size_t)r * N, N);
            }
        }
        return;
    }

    // -------- fallback: global-atomic version --------
    const int* src = ei;
    const int* dst = ei + E;
    const int* rsrc = rei;
    const int* rdst = rei + E;

    float* cnt_f = (float*)d_ws;
    float* cnt_r = cnt_f + N;

    (void)hipMemsetAsync(d_out, 0, (size_t)out_size * sizeof(float), stream);
    (void)hipMemsetAsync(d_ws, 0, (size_t)2 * N * sizeof(float), stream);

    int eb = (E + TPB - 1) / TPB; if (eb > MAX_BLOCKS) eb = MAX_BLOCKS;
    int nb = (N + TPB - 1) / TPB; if (nb > MAX_BLOCKS) nb = MAX_BLOCKS;

    round_first<<<eb, TPB, 0, stream>>>(topic, src, dst, out, cnt_f, E);
    normalize_k<<<nb, TPB, 0, stream>>>(out, cnt_f, N);
    for (int r = 1; r < 4; ++r) {
        round_next<<<eb, TPB, 0, stream>>>(out + (size_t)(r - 1) * N, src, dst,
                                           out + (size_t)r * N, E);
        normalize_k<<<nb, TPB, 0, stream>>>(out + (size_t)r * N, cnt_f, N);
    }
    round_first<<<eb, TPB, 0, stream>>>(topic, rsrc, rdst, out + (size_t)4 * N, cnt_r, E);
    normalize_k<<<nb, TPB, 0, stream>>>(out + (size_t)4 * N, cnt_r, N);
    for (int r = 5; r < 8; ++r) {
        round_next<<<eb, TPB, 0, stream>>>(out + (size_t)(r - 1) * N, rsrc, rdst,
                                           out + (size_t)r * N, E);
        normalize_k<<<nb, TPB, 0, stream>>>(out + (size_t)r * N, cnt_r, N);
    }
}